// Round 4
// baseline (88.119 us; speedup 1.0000x reference)
//
#include <hip/hip_runtime.h>
#include <hip/hip_bf16.h>
#include <math.h>

// SOAP descriptor (radial GTO part) for N=3072 atoms, diagonal periodic box.
// out[i, n*N + j] = mask(d_ij) ? (d_ij/RCUT)^n * exp(-alpha*d_ij^2) : 0
// out[i, 8*N + l] = 0  (l = 0..6, "angular" zeros)
// Row length M = 8*N + 7 = 24583 (odd); out fp32, 302 MB -> store-BW bound.
// v3b: nontemporal dwordx4 stores via ext_vector_type (builtin rejects the
//      HIP_vector_type struct); one block per row, 3 float4-groups/thread.

#define N_ATOMS 3072
#define NMAX    8
#define LP1     7
#define ROWLEN  (NMAX * N_ATOMS + LP1)   // 24583
#define RCUT_F  6.0f
#define ALPHA_F 2.0f                      // 0.5 / sigma^2, sigma = 0.5

typedef float f32x4 __attribute__((ext_vector_type(4)));

__device__ __forceinline__ void pair_vals(float pix, float piy, float piz,
                                          const float* __restrict__ pos, int j,
                                          float c0, float c1, float c2,
                                          float ic0, float ic1, float ic2,
                                          float& v0, float& r) {
    float dx = pix - pos[3 * j + 0];
    float dy = piy - pos[3 * j + 1];
    float dz = piz - pos[3 * j + 2];
    dx -= c0 * rintf(dx * ic0);           // minimum image (round-half-even)
    dy -= c1 * rintf(dy * ic1);
    dz -= c2 * rintf(dz * ic2);
    const float d2 = dx * dx + dy * dy + dz * dz + 1e-10f;
    const float d  = sqrtf(d2);
    const bool  m  = (d < RCUT_F) && (d > 0.1f);
    v0 = m ? __expf(-ALPHA_F * d2) : 0.0f;
    r  = d * (1.0f / RCUT_F);
}

__global__ __launch_bounds__(256)
void soap_kernel_v3(const float* __restrict__ pos,
                    const float* __restrict__ cell,
                    float* __restrict__ out) {
    const int i = blockIdx.x;
    const int t = threadIdx.x;

    const float c0 = cell[0], c1 = cell[4], c2 = cell[8];
    const float ic0 = 1.0f / c0, ic1 = 1.0f / c1, ic2 = 1.0f / c2;

    const float pix = pos[3 * i + 0];
    const float piy = pos[3 * i + 1];
    const float piz = pos[3 * i + 2];

    const int p = i & 3;                   // aligned j-phase for this row
    const int G = (p == 0) ? 768 : 767;    // full float4 groups in the row
    float* const row = out + (size_t)i * ROWLEN;

    // angular zeros (7 per row)
    if (t < LP1) {
        __builtin_nontemporal_store(0.0f, row + NMAX * N_ATOMS + t);
    }

    // boundary elements for misaligned rows: j in [0,p) u [p+3068, 3072)
    if (p != 0 && t < 4) {
        const int jb = (t < p) ? t : (3068 + t);
        float v, r;
        pair_vals(pix, piy, piz, pos, jb, c0, c1, c2, ic0, ic1, ic2, v, r);
        size_t off = (size_t)jb;
#pragma unroll
        for (int n = 0; n < NMAX; ++n) {
            __builtin_nontemporal_store(v, row + off);
            v *= r;
            off += N_ATOMS;
        }
    }

#pragma unroll
    for (int s = 0; s < 3; ++s) {
        const int g = t + 256 * s;
        if (g < G) {
            const int j0 = p + 4 * g;      // 16B-aligned in flat layout
            float v[4], r[4];
#pragma unroll
            for (int e = 0; e < 4; ++e) {
                pair_vals(pix, piy, piz, pos, j0 + e, c0, c1, c2,
                          ic0, ic1, ic2, v[e], r[e]);
            }
            size_t off = (size_t)j0;
#pragma unroll
            for (int n = 0; n < NMAX; ++n) {
                f32x4 q = { v[0], v[1], v[2], v[3] };
                __builtin_nontemporal_store(q,
                    reinterpret_cast<f32x4*>(row + off));
                v[0] *= r[0]; v[1] *= r[1]; v[2] *= r[2]; v[3] *= r[3];
                off += N_ATOMS;
            }
        }
    }
}

extern "C" void kernel_launch(void* const* d_in, const int* in_sizes, int n_in,
                              void* d_out, int out_size, void* d_ws, size_t ws_size,
                              hipStream_t stream) {
    const float* pos  = (const float*)d_in[0];
    // d_in[1] = atom_types (unused by the math)
    const float* cell = (const float*)d_in[2];
    float* out = (float*)d_out;

    dim3 block(256);
    dim3 grid(N_ATOMS, 1);                 // one block per row
    soap_kernel_v3<<<grid, block, 0, stream>>>(pos, cell, out);
}

// Round 5
// 54.340 us; speedup vs baseline: 1.6216x; 1.6216x over previous
//
#include <hip/hip_runtime.h>
#include <hip/hip_bf16.h>
#include <math.h>

// SOAP descriptor (radial GTO part) for N=3072 atoms, diagonal periodic box.
// out[i, n*N + j] = mask(d_ij) ? (d_ij/RCUT)^n * exp(-alpha*d_ij^2) : 0
// out[i, 8*N + l] = 0  (l = 0..6, "angular" zeros)
// Row length M = 8*N + 7 = 24583; out fp32, 302 MB -> store-BW bound.
// v4 = v1 structure (best measured: 53.1 us). Regular cache-allocating
//      scalar stores, 1 j per thread, grid 3072x12. nt stores REGRESSED
//      (88 us: bypasses L2 write-combining); dwordx4 was neutral. Only
//      micro-cleanups vs v1: reciprocal multiply for minimum-image, __expf.

#define N_ATOMS 3072
#define NMAX    8
#define LP1     7
#define ROWLEN  (NMAX * N_ATOMS + LP1)   // 24583
#define RCUT_F  6.0f
#define ALPHA_F 2.0f                      // 0.5 / sigma^2, sigma = 0.5

__global__ __launch_bounds__(256)
void soap_kernel_v4(const float* __restrict__ pos,
                    const float* __restrict__ cell,
                    float* __restrict__ out) {
    const int i = blockIdx.x;
    const int j = blockIdx.y * blockDim.x + threadIdx.x;

    // diagonal cell (input is BOX * eye(3))
    const float c0 = cell[0], c1 = cell[4], c2 = cell[8];
    const float ic0 = 1.0f / c0, ic1 = 1.0f / c1, ic2 = 1.0f / c2;

    float dx = pos[3 * i + 0] - pos[3 * j + 0];
    float dy = pos[3 * i + 1] - pos[3 * j + 1];
    float dz = pos[3 * i + 2] - pos[3 * j + 2];
    // minimum image (round-half-even matches jnp.round; ties are masked out)
    dx -= c0 * rintf(dx * ic0);
    dy -= c1 * rintf(dy * ic1);
    dz -= c2 * rintf(dz * ic2);

    const float d2 = dx * dx + dy * dy + dz * dz + 1e-10f;
    const float d  = sqrtf(d2);
    const bool  m  = (d < RCUT_F) && (d > 0.1f);

    float v = m ? __expf(-ALPHA_F * d2) : 0.0f;   // n = 0 term
    const float r = d * (1.0f / RCUT_F);

    size_t off = (size_t)i * ROWLEN + (size_t)j;
#pragma unroll
    for (int n = 0; n < NMAX; ++n) {
        out[off] = v;
        v *= r;
        off += N_ATOMS;
    }

    // angular zeros (7 per row), written once per row
    if (blockIdx.y == 0 && threadIdx.x < LP1) {
        out[(size_t)i * ROWLEN + (size_t)(NMAX * N_ATOMS) + threadIdx.x] = 0.0f;
    }
}

extern "C" void kernel_launch(void* const* d_in, const int* in_sizes, int n_in,
                              void* d_out, int out_size, void* d_ws, size_t ws_size,
                              hipStream_t stream) {
    const float* pos  = (const float*)d_in[0];
    // d_in[1] = atom_types (unused by the math)
    const float* cell = (const float*)d_in[2];
    float* out = (float*)d_out;

    dim3 block(256);
    dim3 grid(N_ATOMS, N_ATOMS / 256);    // 3072 x 12
    soap_kernel_v4<<<grid, block, 0, stream>>>(pos, cell, out);
}